// Round 4
// baseline (436.577 us; speedup 1.0000x reference)
//
#include <hip/hip_runtime.h>

// TreeAttentionV2: B=8, T=1024, C=1024 (L=4,R=256), H=16, hd=64.
// Pipeline (all fp16 MFMA, fp32 accumulate):
//   1. conv_x:      x fp32 (8192x1024) -> xh fp16
//   2. tconv:       w_attn fp32 (1024x3072) -> waT fp16 (3072x1024)   [B^T for GEMM]
//   3. tconv:       w_proj fp32 (1024x1024) -> wpT fp16 (1024x1024)
//   4. gemm<f16>:   qkv = xh @ waT^T + b_attn  -> fp16 (8192x3072)
//   5. vtrans:      v section -> vT (128 heads)(64 x 1024)            [V^T for PV MFMA]
//   6. attn v4:     16-row q-tiles, 512 thr / 8 waves, 33KB LDS -> 4 blocks/CU.
//                   Phase1: S^T=K.Q^T, exp->E + reg rowsum -> lsum. (1 barrier)
//                   Phase2: k-sliced PV, normalize+threshold fused into A-fragment
//                   regs (pk_fma/pk_max). (barrier) Phase3: LDS-reduce 8 partials.
//   7. gemm<f32>:   out = y @ wpT^T + b_proj -> fp32 d_out
//
// Workspace layout (needs >= 92,274,688 B):
//   [0, 48M)   qkv fp16
//   [48M,64M)  vT  fp16
//   [64M,80M)  xh fp16 (reused as y after gemm1 consumes it)
//   [80M,86M)  waT fp16
//   [86M,88M)  wpT fp16

typedef _Float16 half8 __attribute__((ext_vector_type(8)));
typedef _Float16 half4_t __attribute__((ext_vector_type(4)));
typedef _Float16 half2_t __attribute__((ext_vector_type(2)));
typedef float floatx4 __attribute__((ext_vector_type(4)));

__device__ __forceinline__ void gl2lds16(const void* gsrc, void* lds) {
    __builtin_amdgcn_global_load_lds(
        (const __attribute__((address_space(1))) unsigned int*)gsrc,
        (__attribute__((address_space(3))) unsigned int*)lds,
        16, 0, 0);
}

// ---------------- elementwise convert fp32 -> fp16 ----------------
__global__ __launch_bounds__(256) void conv_x(const float4* __restrict__ in,
                                              _Float16* __restrict__ out, int n4) {
    int idx = blockIdx.x * blockDim.x + threadIdx.x;
    int stride = gridDim.x * blockDim.x;
    for (int i = idx; i < n4; i += stride) {
        float4 v = in[i];
        half4_t h = { (_Float16)v.x, (_Float16)v.y, (_Float16)v.z, (_Float16)v.w };
        *(half4_t*)(out + (size_t)i * 4) = h;
    }
}

// ------------- transpose + convert: out[n][k] = in[k][n] ----------
__global__ __launch_bounds__(256) void tconv(const float* __restrict__ in,
                                             _Float16* __restrict__ out, int R, int C) {
    __shared__ _Float16 t[64 * 65];
    int bx = blockIdx.x, by = blockIdx.y;
#pragma unroll
    for (int it = 0; it < 16; ++it) {
        int idx = it * 256 + threadIdx.x;
        int r = idx >> 6, c = idx & 63;
        t[c * 65 + r] = (_Float16)in[(size_t)(by * 64 + r) * C + bx * 64 + c];
    }
    __syncthreads();
#pragma unroll
    for (int it = 0; it < 16; ++it) {
        int idx = it * 256 + threadIdx.x;
        int rn = idx >> 6, ck = idx & 63;
        out[(size_t)(bx * 64 + rn) * R + by * 64 + ck] = t[rn * 65 + ck];
    }
}

// ------------- V transpose: vT[bh*64+d][t] = qkv[b,t, 2048+h*64+d] -------------
__global__ __launch_bounds__(256) void vtrans(const _Float16* __restrict__ qkv,
                                              _Float16* __restrict__ vT) {
    __shared__ _Float16 t[64 * 65];
    int t0 = blockIdx.x * 64;
    int bh = blockIdx.y;
    int b = bh >> 4, h = bh & 15;
#pragma unroll
    for (int it = 0; it < 16; ++it) {
        int idx = it * 256 + threadIdx.x;
        int tt = idx >> 6, d = idx & 63;
        t[d * 65 + tt] = qkv[(size_t)(b * 1024 + t0 + tt) * 3072 + 2048 + h * 64 + d];
    }
    __syncthreads();
#pragma unroll
    for (int it = 0; it < 16; ++it) {
        int idx = it * 256 + threadIdx.x;
        int dd = idx >> 6, tt = idx & 63;
        vT[(size_t)(bh * 64 + dd) * 1024 + t0 + tt] = t[dd * 65 + tt];
    }
}

// ------------- m97-style GEMM: C(MxN) = A(MxK) * BT(NxK)^T + bias -------------
template <bool F16OUT>
__global__ __launch_bounds__(256) void gemm_tn(const _Float16* __restrict__ A,
                                               const _Float16* __restrict__ BT,
                                               const float* __restrict__ bias,
                                               void* __restrict__ Cout, int N) {
    constexpr int K = 1024;
    __shared__ __attribute__((aligned(16))) _Float16 sA[128 * 32];
    __shared__ __attribute__((aligned(16))) _Float16 sB[128 * 32];
    int tid = threadIdx.x;
    int W = tid >> 6, lane = tid & 63, quad = lane >> 4, l15 = lane & 15;
    int m0 = blockIdx.y * 128, n0 = blockIdx.x * 128;
    int wr = (W >> 1) * 64, wc = (W & 1) * 64;
    floatx4 acc[4][4] = {};

    for (int kt = 0; kt < K / 32; ++kt) {
        int k0 = kt * 32;
#pragma unroll
        for (int rho = 0; rho < 2; ++rho) {
            int lin = rho * 256 + tid;                 // 16B chunk id, tile row-major
            const _Float16* gA = A + (size_t)(m0 + (lin >> 2)) * K + k0 + (lin & 3) * 8;
            const _Float16* gB = BT + (size_t)(n0 + (lin >> 2)) * K + k0 + (lin & 3) * 8;
            int ldsoff = __builtin_amdgcn_readfirstlane((rho * 256 + W * 64) * 16);
            gl2lds16(gA, (char*)sA + ldsoff);
            gl2lds16(gB, (char*)sB + ldsoff);
        }
        __syncthreads();
        half8 a[4], b[4];
#pragma unroll
        for (int rf = 0; rf < 4; ++rf)
            a[rf] = *(const half8*)(sA + (wr + rf * 16 + l15) * 32 + quad * 8);
#pragma unroll
        for (int cf = 0; cf < 4; ++cf)
            b[cf] = *(const half8*)(sB + (wc + cf * 16 + l15) * 32 + quad * 8);
#pragma unroll
        for (int rf = 0; rf < 4; ++rf)
#pragma unroll
            for (int cf = 0; cf < 4; ++cf)
                acc[rf][cf] = __builtin_amdgcn_mfma_f32_16x16x32_f16(a[rf], b[cf], acc[rf][cf], 0, 0, 0);
        __syncthreads();
    }
#pragma unroll
    for (int cf = 0; cf < 4; ++cf) {
        int gn = n0 + wc + cf * 16 + l15;
        float bv = bias[gn];
#pragma unroll
        for (int rf = 0; rf < 4; ++rf) {
            int gmBase = m0 + wr + rf * 16 + quad * 4;
#pragma unroll
            for (int r = 0; r < 4; ++r) {
                float v = acc[rf][cf][r] + bv;
                size_t off = (size_t)(gmBase + r) * N + gn;
                if (F16OUT) ((_Float16*)Cout)[off] = (_Float16)v;
                else        ((float*)Cout)[off] = v;
            }
        }
    }
}

// ------------------------------- attention v4 -------------------------------
// grid (64 q-tiles of 16 rows, 128 bh), 512 threads = 8 waves; 4 blocks/CU.
// Wave w owns k-slice [w*128, w*128+128).
// LDS: E = 16 q-rows x 1024 k fp16 (32KB), xor-swizzled 16B granules; lsum 8x16 f32.
__device__ __forceinline__ int esw(int row, int colByte) {
    return row * 2048 + (colByte ^ ((row & 7) << 4));
}

__global__ __launch_bounds__(512, 8) void attn(const _Float16* __restrict__ qkv,
                                               const _Float16* __restrict__ vT,
                                               _Float16* __restrict__ y) {
    __shared__ __attribute__((aligned(16))) _Float16 E[16 * 1024];
    __shared__ float lsum[8][16];
    char* Eb = (char*)E;
    int tid = threadIdx.x;
    int W = tid >> 6, lane = tid & 63, quad = lane >> 4, l15 = lane & 15;
    int qt = blockIdx.x, bh = blockIdx.y;
    int b = bh >> 4, h = bh & 15;
    int q0 = qt * 16;

    // --- Q as B-fragments (B[k=quad*8+j][n=l15]): n = q-row, k = d ---
    half8 bq[2];
#pragma unroll
    for (int ks = 0; ks < 2; ++ks)
        bq[ks] = *(const half8*)(qkv + (size_t)(b * 1024 + q0 + l15) * 3072 +
                                 h * 64 + ks * 32 + quad * 8);

    // --- Phase 1: S^T = K.Q^T (scaled), e = exp(s) -> E; rowsum in regs ---
    // C-layout of S^T tile: col(l15) = q, row(quad*4+r) = k -> 4 consecutive k per lane.
    float lpart = 0.f;   // lane's partial rowsum for q = l15
#pragma unroll 4
    for (int mt = 0; mt < 8; ++mt) {
        int tk = W * 128 + mt * 16 + l15;
        const _Float16* kp = qkv + (size_t)(b * 1024 + tk) * 3072 + 1024 + h * 64 + quad * 8;
        half8 ak0 = *(const half8*)(kp);
        half8 ak1 = *(const half8*)(kp + 32);
        floatx4 s = {};
        s = __builtin_amdgcn_mfma_f32_16x16x32_f16(ak0, bq[0], s, 0, 0, 0);
        s = __builtin_amdgcn_mfma_f32_16x16x32_f16(ak1, bq[1], s, 0, 0, 0);
        half4_t h4;
#pragma unroll
        for (int r = 0; r < 4; ++r) {
            float e = __expf(fminf(s[r] * 0.125f, 10.0f));  // exp(10)=22026 < fp16 max
            lpart += e;
            h4[r] = (_Float16)e;
        }
        int kbyte = W * 256 + mt * 32 + quad * 8;
        *(half4_t*)(Eb + l15 * 2048 + (kbyte ^ ((l15 & 7) << 4))) = h4;
    }
    // reduce over the 4 quads (lanes sharing l15)
    lpart += __shfl_xor(lpart, 16);
    lpart += __shfl_xor(lpart, 32);
    if (lane < 16) lsum[W][l15] = lpart;
    __syncthreads();

    // --- Phase 2: PV over wave's k-slice, normalize+threshold fused in regs ---
    float l = 0.f;
#pragma unroll
    for (int w = 0; w < 8; ++w) l += lsum[w][l15];
    _Float16 invh = (_Float16)(1.0f / l);
    half8 inv8, t8, z8;
#pragma unroll
    for (int j = 0; j < 8; ++j) { inv8[j] = invh; t8[j] = (_Float16)(-0.001f); z8[j] = (_Float16)0.f; }

    floatx4 acc[4] = {};
#pragma unroll
    for (int kt = 0; kt < 4; ++kt) {
        int kbyte = W * 256 + kt * 64 + quad * 16;
        half8 ap = *(const half8*)(Eb + l15 * 2048 + (kbyte ^ ((l15 & 7) << 4)));
        ap = ap * inv8 + t8;                            // v_pk_fma_f16
        ap = __builtin_elementwise_max(ap, z8);         // v_pk_max_f16
        const _Float16* vbase = vT + (size_t)(bh * 64 + l15) * 1024 + W * 128 + kt * 32 + quad * 8;
        half8 bv0 = *(const half8*)(vbase);
        half8 bv1 = *(const half8*)(vbase + 16 * 1024);
        half8 bv2 = *(const half8*)(vbase + 32 * 1024);
        half8 bv3 = *(const half8*)(vbase + 48 * 1024);
        acc[0] = __builtin_amdgcn_mfma_f32_16x16x32_f16(ap, bv0, acc[0], 0, 0, 0);
        acc[1] = __builtin_amdgcn_mfma_f32_16x16x32_f16(ap, bv1, acc[1], 0, 0, 0);
        acc[2] = __builtin_amdgcn_mfma_f32_16x16x32_f16(ap, bv2, acc[2], 0, 0, 0);
        acc[3] = __builtin_amdgcn_mfma_f32_16x16x32_f16(ap, bv3, acc[3], 0, 0, 0);
    }
    __syncthreads();   // all waves done reading E before reuse as reduce buffer

    // --- Phase 3: LDS-reduce the 8 k-slice partials (reuse E: 8x16x64 f32 = 32KB) ---
    float* red = (float*)E;
#pragma unroll
    for (int cf = 0; cf < 4; ++cf)
#pragma unroll
        for (int r = 0; r < 4; ++r)
            red[W * 1024 + (quad * 4 + r) * 64 + cf * 16 + l15] = acc[cf][r];
    __syncthreads();
    {
        int e2 = tid * 2;                // 512 thr x 2 = 1024 = 16x64
        int r = e2 >> 6, c = e2 & 63;
        float s0 = 0.f, s1 = 0.f;
#pragma unroll
        for (int w = 0; w < 8; ++w) {
            s0 += red[w * 1024 + e2];
            s1 += red[w * 1024 + e2 + 1];
        }
        half2_t hv = { (_Float16)s0, (_Float16)s1 };
        *(half2_t*)(y + (size_t)(b * 1024 + q0 + r) * 1024 + h * 64 + c) = hv;
    }
}

// ------------------------------- launcher -------------------------------
extern "C" void kernel_launch(void* const* d_in, const int* in_sizes, int n_in,
                              void* d_out, int out_size, void* d_ws, size_t ws_size,
                              hipStream_t stream) {
    const float* x  = (const float*)d_in[0];
    const float* wa = (const float*)d_in[1];
    const float* ba = (const float*)d_in[2];
    const float* wp = (const float*)d_in[3];
    const float* bp = (const float*)d_in[4];
    float* out = (float*)d_out;

    char* ws = (char*)d_ws;
    _Float16* qkv = (_Float16*)(ws);                    // 48 MiB
    _Float16* vT  = (_Float16*)(ws + 50331648);         // 16 MiB
    _Float16* xh  = (_Float16*)(ws + 67108864);         // 16 MiB (reused as y)
    _Float16* waT = (_Float16*)(ws + 83886080);         // 6 MiB
    _Float16* wpT = (_Float16*)(ws + 90177536);         // 2 MiB

    conv_x<<<4096, 256, 0, stream>>>((const float4*)x, xh, 8388608 / 4);
    tconv<<<dim3(48, 16), 256, 0, stream>>>(wa, waT, 1024, 3072);
    tconv<<<dim3(16, 16), 256, 0, stream>>>(wp, wpT, 1024, 1024);
    gemm_tn<true><<<dim3(24, 64), 256, 0, stream>>>(xh, waT, ba, (void*)qkv, 3072);
    vtrans<<<dim3(16, 128), 256, 0, stream>>>(qkv, vT);
    attn<<<dim3(64, 128), 512, 0, stream>>>(qkv, vT, xh);
    gemm_tn<false><<<dim3(8, 64), 256, 0, stream>>>(xh, wpT, bp, (void*)out, 1024);
}

// Round 6
// 287.863 us; speedup vs baseline: 1.5166x; 1.5166x over previous
//
#include <hip/hip_runtime.h>

// TreeAttentionV2: B=8, T=1024, C=1024 (L=4,R=256), H=16, hd=64.
// Pipeline (all fp16 MFMA, fp32 accumulate):
//   1. conv_x:    x fp32 (8192x1024) -> xh fp16
//   2. tconv x2:  w_attn -> waT fp16 (3072x1024), w_proj -> wpT fp16 (1024x1024)
//   3. gemm<split3>: qn/kn/vn = xh @ waT^T + b_attn -> three separate fp16 (8192x1024)
//                 (128-col tiles never straddle a section; sec = n0>>10 wave-uniform)
//   4. pack_k:    kn -> kP, MFMA-A-fragment order (wave loads = 1KB contiguous)
//   5. pack_v:    vn -> vP, MFMA-B-fragment order (wave loads = 1KB contiguous)
//   6. attn v6:   32-row q-tile, 8 waves, k-sliced. Phase1 S^T=K.Q^T, exp->E(LDS,
//                 swizzled) + reg rowsum. Phase2 PV, normalize+threshold fused into
//                 A-fragments (pk_fma/pk_max). Phase3 LDS-reduce 8 partials.
//   7. gemm<f32>: out = y @ wpT^T + b_proj -> fp32 d_out
//
// Workspace (88 MiB, same proven budget; aliases are now truly-dead standalone bufs):
//   [0,16M)   xh   (dead after gemm1) -> vP
//   [16M,32M) qn   (live through attn)
//   [32M,48M) kn   (dead after pack_k) -> y
//   [48M,64M) vn   (dead after pack_v)
//   [64M,80M) kP
//   [80M,86M) waT
//   [86M,88M) wpT

typedef _Float16 half8 __attribute__((ext_vector_type(8)));
typedef _Float16 half4_t __attribute__((ext_vector_type(4)));
typedef float floatx4 __attribute__((ext_vector_type(4)));

__device__ __forceinline__ void gl2lds16(const void* gsrc, void* lds) {
    __builtin_amdgcn_global_load_lds(
        (const __attribute__((address_space(1))) unsigned int*)gsrc,
        (__attribute__((address_space(3))) unsigned int*)lds,
        16, 0, 0);
}

// ---------------- elementwise convert fp32 -> fp16 ----------------
__global__ __launch_bounds__(256) void conv_x(const float4* __restrict__ in,
                                              _Float16* __restrict__ out, int n4) {
    int idx = blockIdx.x * blockDim.x + threadIdx.x;
    int stride = gridDim.x * blockDim.x;
    for (int i = idx; i < n4; i += stride) {
        float4 v = in[i];
        half4_t h = { (_Float16)v.x, (_Float16)v.y, (_Float16)v.z, (_Float16)v.w };
        *(half4_t*)(out + (size_t)i * 4) = h;
    }
}

// ------------- transpose + convert: out[n][k] = in[k][n] ----------
__global__ __launch_bounds__(256) void tconv(const float* __restrict__ in,
                                             _Float16* __restrict__ out, int R, int C) {
    __shared__ _Float16 t[64 * 65];
    int bx = blockIdx.x, by = blockIdx.y;
#pragma unroll
    for (int it = 0; it < 16; ++it) {
        int idx = it * 256 + threadIdx.x;
        int r = idx >> 6, c = idx & 63;
        t[c * 65 + r] = (_Float16)in[(size_t)(by * 64 + r) * C + bx * 64 + c];
    }
    __syncthreads();
#pragma unroll
    for (int it = 0; it < 16; ++it) {
        int idx = it * 256 + threadIdx.x;
        int rn = idx >> 6, ck = idx & 63;
        out[(size_t)(bx * 64 + rn) * R + by * 64 + ck] = t[rn * 65 + ck];
    }
}

// ------------- pack K into A-fragment order -------------
// kP chunk layout (16B units): [bh][kb=64 (16 t-rows)][half=2][lane=quad*16+l15]
// lane holds K[t=kb*16+l15][d=half*32+quad*8 .. +8)
__global__ __launch_bounds__(256) void pack_k(const _Float16* __restrict__ kn,
                                              _Float16* __restrict__ kP) {
    int cid = blockIdx.x * 256 + threadIdx.x;        // 16B chunk id, 1M total
    int lane = cid & 63, half = (cid >> 6) & 1, kb = (cid >> 7) & 63, bh = cid >> 13;
    int l15 = lane & 15, quad = lane >> 4;
    int b = bh >> 4, h = bh & 15;
    int t = kb * 16 + l15, d = half * 32 + quad * 8;
    half8 v = *(const half8*)(kn + (size_t)(b * 1024 + t) * 1024 + h * 64 + d);
    *(half8*)(kP + (size_t)cid * 8) = v;
}

// ------------- pack V (transposed) into B-fragment order -------------
// vP chunk layout: [bh][kbv=32 (32 k)][cf=4][quad=4][l15v=16]
// chunk holds V^T[d=cf*16+l15v][k=kbv*32+quad*8 .. +8)
__global__ __launch_bounds__(256) void pack_v(const _Float16* __restrict__ vn,
                                              _Float16* __restrict__ vP) {
    __shared__ _Float16 s[32][72];                   // 32 k-rows x 64 d, padded
    int kbv = blockIdx.x, bh = blockIdx.y;
    int b = bh >> 4, h = bh & 15;
    int tid = threadIdx.x;
    {
        int row = tid >> 3, piece = tid & 7;
        *(half8*)&s[row][piece * 8] =
            *(const half8*)(vn + (size_t)(b * 1024 + kbv * 32 + row) * 1024 + h * 64 + piece * 8);
    }
    __syncthreads();
    {
        int l15v = tid & 15, quad = (tid >> 4) & 3, cf = tid >> 6;
        half8 o;
#pragma unroll
        for (int j = 0; j < 8; ++j) o[j] = s[quad * 8 + j][cf * 16 + l15v];
        *(half8*)(vP + ((size_t)(bh * 32 + kbv) * 256 + tid) * 8) = o;
    }
}

// ------------- m97-style GEMM: C(MxN) = A(MxK) * BT(NxK)^T + bias -------------
// SPLIT3: N=3072, fp16 out scattered to o0/o1/o2 (each 8192x1024, col = gn&1023).
// else:   fp32 out to o0 with row stride N.
template <bool SPLIT3>
__global__ __launch_bounds__(256) void gemm_tn(const _Float16* __restrict__ A,
                                               const _Float16* __restrict__ BT,
                                               const float* __restrict__ bias,
                                               void* __restrict__ o0, void* __restrict__ o1,
                                               void* __restrict__ o2, int N) {
    constexpr int K = 1024;
    __shared__ __attribute__((aligned(16))) _Float16 sA[128 * 32];
    __shared__ __attribute__((aligned(16))) _Float16 sB[128 * 32];
    int tid = threadIdx.x;
    int W = tid >> 6, lane = tid & 63, quad = lane >> 4, l15 = lane & 15;
    int m0 = blockIdx.y * 128, n0 = blockIdx.x * 128;
    int wr = (W >> 1) * 64, wc = (W & 1) * 64;
    floatx4 acc[4][4] = {};

    for (int kt = 0; kt < K / 32; ++kt) {
        int k0 = kt * 32;
#pragma unroll
        for (int rho = 0; rho < 2; ++rho) {
            int lin = rho * 256 + tid;                 // 16B chunk id, tile row-major
            const _Float16* gA = A + (size_t)(m0 + (lin >> 2)) * K + k0 + (lin & 3) * 8;
            const _Float16* gB = BT + (size_t)(n0 + (lin >> 2)) * K + k0 + (lin & 3) * 8;
            int ldsoff = __builtin_amdgcn_readfirstlane((rho * 256 + W * 64) * 16);
            gl2lds16(gA, (char*)sA + ldsoff);
            gl2lds16(gB, (char*)sB + ldsoff);
        }
        __syncthreads();
        half8 a[4], b[4];
#pragma unroll
        for (int rf = 0; rf < 4; ++rf)
            a[rf] = *(const half8*)(sA + (wr + rf * 16 + l15) * 32 + quad * 8);
#pragma unroll
        for (int cf = 0; cf < 4; ++cf)
            b[cf] = *(const half8*)(sB + (wc + cf * 16 + l15) * 32 + quad * 8);
#pragma unroll
        for (int rf = 0; rf < 4; ++rf)
#pragma unroll
            for (int cf = 0; cf < 4; ++cf)
                acc[rf][cf] = __builtin_amdgcn_mfma_f32_16x16x32_f16(a[rf], b[cf], acc[rf][cf], 0, 0, 0);
        __syncthreads();
    }
    // section select is wave-uniform: 128-col tiles never straddle 1024 boundaries
    _Float16* hbase = nullptr;
    if (SPLIT3) {
        int sec = n0 >> 10;
        hbase = (_Float16*)(sec == 0 ? o0 : (sec == 1 ? o1 : o2));
    }
#pragma unroll
    for (int cf = 0; cf < 4; ++cf) {
        int gn = n0 + wc + cf * 16 + l15;
        float bv = bias[gn];
        int cn = gn & 1023;
#pragma unroll
        for (int rf = 0; rf < 4; ++rf) {
            int gmBase = m0 + wr + rf * 16 + quad * 4;
#pragma unroll
            for (int r = 0; r < 4; ++r) {
                float v = acc[rf][cf][r] + bv;
                if (SPLIT3) hbase[(size_t)(gmBase + r) * 1024 + cn] = (_Float16)v;
                else        ((float*)o0)[(size_t)(gmBase + r) * N + gn] = v;
            }
        }
    }
}

// ------------------------------- attention v6 -------------------------------
// grid (32 q-tiles of 32 rows, 128 bh), 512 threads = 8 waves.
// Wave w owns k-slice [w*128, w*128+128).
// LDS: E = 32 q-rows x 1024 k fp16 (64KB), xor-swizzled 16B granules; lsum 8x32 f32.
__device__ __forceinline__ int esw(int row, int colByte) {
    return row * 2048 + (colByte ^ ((row & 7) << 4));
}

__global__ __launch_bounds__(512, 4) void attn(const _Float16* __restrict__ qn,
                                               const _Float16* __restrict__ kP,
                                               const _Float16* __restrict__ vP,
                                               _Float16* __restrict__ y) {
    __shared__ __attribute__((aligned(16))) _Float16 E[32 * 1024];
    __shared__ float lsum[8][32];
    char* Eb = (char*)E;
    int tid = threadIdx.x;
    int W = tid >> 6, lane = tid & 63, quad = lane >> 4, l15 = lane & 15;
    int qt = blockIdx.x, bh = blockIdx.y;
    int b = bh >> 4, h = bh & 15;
    int q0 = qt * 32;

    // --- Q as B-fragments (B[k=quad*8+j][n=l15]): n = q-row, k = d ---
    half8 bq[2][2];
#pragma unroll
    for (int nf = 0; nf < 2; ++nf)
#pragma unroll
        for (int ks = 0; ks < 2; ++ks)
            bq[nf][ks] = *(const half8*)(qn + (size_t)(b * 1024 + q0 + nf * 16 + l15) * 1024 +
                                         h * 64 + ks * 32 + quad * 8);

    // --- Phase 1: S^T = K.Q^T (scaled), e = exp(s) -> E; rowsum partials in regs ---
    float lpart[2] = {0.f, 0.f};   // lane's partial rowsum for q = nf*16 + l15
#pragma unroll 4
    for (int mt = 0; mt < 8; ++mt) {
        int kb = W * 8 + mt;
        const _Float16* kp = kP + ((size_t)(bh * 64 + kb) * 128 + lane) * 8;
        half8 ak0 = *(const half8*)(kp);            // contiguous 1KB per wave
        half8 ak1 = *(const half8*)(kp + 512);
#pragma unroll
        for (int nf = 0; nf < 2; ++nf) {
            floatx4 s = {};
            s = __builtin_amdgcn_mfma_f32_16x16x32_f16(ak0, bq[nf][0], s, 0, 0, 0);
            s = __builtin_amdgcn_mfma_f32_16x16x32_f16(ak1, bq[nf][1], s, 0, 0, 0);
            half4_t h4;
#pragma unroll
            for (int r = 0; r < 4; ++r) {
                float e = __expf(fminf(s[r] * 0.125f, 10.0f));  // exp(10)=22026 < fp16 max
                lpart[nf] += e;
                h4[r] = (_Float16)e;
            }
            int q = nf * 16 + l15;
            int kbyte = (W * 128 + mt * 16 + quad * 4) * 2;
            *(half4_t*)(Eb + q * 2048 + (kbyte ^ ((q & 7) << 4))) = h4;
        }
    }
    // reduce over the 4 quads (lanes sharing l15)
#pragma unroll
    for (int nf = 0; nf < 2; ++nf) {
        lpart[nf] += __shfl_xor(lpart[nf], 16);
        lpart[nf] += __shfl_xor(lpart[nf], 32);
    }
    if (lane < 16) {
        lsum[W][l15] = lpart[0];
        lsum[W][16 + l15] = lpart[1];
    }
    __syncthreads();

    // --- Phase 2: PV over wave's k-slice; normalize+threshold fused in regs ---
    half8 inv8[2], t8, z8;
#pragma unroll
    for (int j = 0; j < 8; ++j) { t8[j] = (_Float16)(-0.001f); z8[j] = (_Float16)0.f; }
#pragma unroll
    for (int rf = 0; rf < 2; ++rf) {
        float l = 0.f;
#pragma unroll
        for (int w = 0; w < 8; ++w) l += lsum[w][rf * 16 + l15];
        _Float16 invh = (_Float16)(1.0f / l);
#pragma unroll
        for (int j = 0; j < 8; ++j) inv8[rf][j] = invh;
    }

    floatx4 acc[2][4] = {};
#pragma unroll
    for (int kt = 0; kt < 4; ++kt) {
        int kk = W * 128 + kt * 32;
        half8 ap[2];
#pragma unroll
        for (int rf = 0; rf < 2; ++rf) {
            ap[rf] = *(const half8*)(Eb + esw(rf * 16 + l15, (kk + quad * 8) * 2));
            ap[rf] = ap[rf] * inv8[rf] + t8;                        // v_pk_fma_f16
            ap[rf] = __builtin_elementwise_max(ap[rf], z8);         // v_pk_max_f16
        }
        const _Float16* vbase = vP + ((size_t)(bh * 32 + (W * 4 + kt)) * 256 + lane) * 8;
        half8 bv[4];
#pragma unroll
        for (int cf = 0; cf < 4; ++cf)
            bv[cf] = *(const half8*)(vbase + cf * 512);             // contiguous 1KB / wave
#pragma unroll
        for (int rf = 0; rf < 2; ++rf)
#pragma unroll
            for (int cf = 0; cf < 4; ++cf)
                acc[rf][cf] = __builtin_amdgcn_mfma_f32_16x16x32_f16(ap[rf], bv[cf], acc[rf][cf], 0, 0, 0);
    }
    __syncthreads();   // all waves done reading E before reuse

    // --- Phase 3: LDS-reduce the 8 k-slice partials (reuse E: 8x32x64 f32 = 64KB) ---
    float* red = (float*)E;
#pragma unroll
    for (int rf = 0; rf < 2; ++rf)
#pragma unroll
        for (int cf = 0; cf < 4; ++cf)
#pragma unroll
            for (int r = 0; r < 4; ++r)
                red[W * 2048 + (rf * 16 + quad * 4 + r) * 64 + cf * 16 + l15] = acc[rf][cf][r];
    __syncthreads();
    {
        int e4 = tid * 4;                 // 512 thr x 4 = 2048 = 32x64
        int r = e4 >> 6, c = e4 & 63;
        floatx4 s = {};
#pragma unroll
        for (int w = 0; w < 8; ++w) s += *(const floatx4*)(red + w * 2048 + e4);
        half4_t hv = { (_Float16)s[0], (_Float16)s[1], (_Float16)s[2], (_Float16)s[3] };
        *(half4_t*)(y + (size_t)(b * 1024 + q0 + r) * 1024 + h * 64 + c) = hv;
    }
}

// ------------------------------- launcher -------------------------------
extern "C" void kernel_launch(void* const* d_in, const int* in_sizes, int n_in,
                              void* d_out, int out_size, void* d_ws, size_t ws_size,
                              hipStream_t stream) {
    const float* x  = (const float*)d_in[0];
    const float* wa = (const float*)d_in[1];
    const float* ba = (const float*)d_in[2];
    const float* wp = (const float*)d_in[3];
    const float* bp = (const float*)d_in[4];
    float* out = (float*)d_out;

    char* ws = (char*)d_ws;
    _Float16* xh  = (_Float16*)(ws);                    // [0,16M)  dead after gemm1
    _Float16* vP  = (_Float16*)(ws);                    //   -> vP (pack_v onward)
    _Float16* qn  = (_Float16*)(ws + 16777216);         // [16M,32M) live through attn
    _Float16* kn  = (_Float16*)(ws + 33554432);         // [32M,48M) dead after pack_k
    _Float16* y   = (_Float16*)(ws + 33554432);         //   -> y (attn onward)
    _Float16* vn  = (_Float16*)(ws + 50331648);         // [48M,64M) dead after pack_v
    _Float16* kP  = (_Float16*)(ws + 67108864);         // [64M,80M)
    _Float16* waT = (_Float16*)(ws + 83886080);         // [80M,86M)
    _Float16* wpT = (_Float16*)(ws + 90177536);         // [86M,88M)

    conv_x<<<4096, 256, 0, stream>>>((const float4*)x, xh, 8388608 / 4);
    tconv<<<dim3(48, 16), 256, 0, stream>>>(wa, waT, 1024, 3072);
    tconv<<<dim3(16, 16), 256, 0, stream>>>(wp, wpT, 1024, 1024);
    gemm_tn<true><<<dim3(24, 64), 256, 0, stream>>>(xh, waT, ba, (void*)qn, (void*)kn, (void*)vn, 3072);
    pack_k<<<4096, 256, 0, stream>>>(kn, kP);
    pack_v<<<dim3(32, 128), 256, 0, stream>>>(vn, vP);
    attn<<<dim3(32, 128), 512, 0, stream>>>(qn, kP, vP, y);
    gemm_tn<false><<<dim3(8, 64), 256, 0, stream>>>(y, wpT, bp, (void*)out, nullptr, nullptr, 1024);
}